// Round 1
// baseline (1142.288 us; speedup 1.0000x reference)
//
#include <hip/hip_runtime.h>
#include <math.h>

#define N_PART 32768
#define M_STEPS 50
#define HID 128
#define BLOCK 256

// tanh(x) = 1 - 2/(exp(2x)+1); handles +/-inf saturation correctly.
__device__ __forceinline__ float fast_tanh(float x) {
    float e = __expf(2.0f * x);
    return 1.0f - __fdividef(2.0f, e + 1.0f);
}

// 4 threads per particle: thread t computes hidden units j = jj*4 + t (jj in [0,32)),
// accumulates partial Z[32], butterfly all-reduce over the 4-lane group.
__global__ __launch_bounds__(BLOCK, 2)
void fused_sde(const float* __restrict__ obs,
               const float* __restrict__ x0,
               const float* __restrict__ v0,
               const float* __restrict__ noise,
               const float* __restrict__ gW1,
               const float* __restrict__ gb1,
               const float* __restrict__ gW2,
               const float* __restrict__ gb2,
               const float* __restrict__ gtheta,
               const int* __restrict__ gobs_idx,
               const int* __restrict__ gctrl,
               float* __restrict__ outX,
               float* __restrict__ outV)
{
    // W1 transposed: sW1T[j][k], row padded to 44 floats (176 B, 16B-aligned).
    // W2: sW2[j][d], row padded to 36 floats (144 B, 16B-aligned).
    __shared__ float sW1T[HID * 44];
    __shared__ float sb1[HID];
    __shared__ float sW2[HID * 36];
    __shared__ float sb2[32];

    const int tid = threadIdx.x;

    // Stage weights. W1 is (42,128) row-major [k][j] -> transpose into [j][k+pad].
    for (int j = tid; j < HID; j += BLOCK) {
        for (int k = 0; k < 42; ++k) sW1T[j * 44 + k] = gW1[k * HID + j];
        sW1T[j * 44 + 42] = 0.0f;
        sW1T[j * 44 + 43] = 0.0f;
    }
    for (int i = tid; i < HID; i += BLOCK) sb1[i] = gb1[i];
    for (int i = tid; i < HID * 32; i += BLOCK) {
        int j = i >> 5, d = i & 31;
        sW2[j * 36 + d] = gW2[i];
    }
    for (int i = tid; i < 32; i += BLOCK) sb2[i] = gb2[i];
    __syncthreads();

    const int gid  = blockIdx.x * BLOCK + tid;
    const int part = gid >> 2;   // particle index
    const int t    = tid & 3;    // sub-thread within particle group

    float X[32];
    #pragma unroll
    for (int d = 0; d < 32; ++d) X[d] = x0[(size_t)part * 32 + d];
    float V = v0[part];

    float Y[8];
    #pragma unroll
    for (int k = 0; k < 8; ++k) Y[k] = obs[k];

    const float theta = gtheta[0];
    const float tfeat = (float)gobs_idx[0];
    const float cr    = (float)gctrl[0];
    const float dt      = 0.02f;            // INTERVAL / M_STEPS
    const float sqrt_dt = sqrtf(0.02f);

    // noise[m][part][0..31] as 8 float4s; all 4 group lanes read identical
    // addresses (coalescer dedups). Register double-buffer across steps.
    const float4* nbase = (const float4*)noise + (size_t)part * 8;
    float4 cur[8];
    #pragma unroll
    for (int q = 0; q < 8; ++q) cur[q] = nbase[q];

    for (int m = 0; m < M_STEPS; ++m) {
        float4 nxt[8];
        if (m + 1 < M_STEPS) {
            const float4* np = nbase + (size_t)(m + 1) * (N_PART * 8);
            #pragma unroll
            for (int q = 0; q < 8; ++q) nxt[q] = np[q];
        }

        const float s = (float)m * dt;   // times[m] = m/50

        float Z[32];
        #pragma unroll
        for (int d = 0; d < 32; ++d) Z[d] = 0.0f;

        #pragma unroll 2
        for (int jj = 0; jj < 32; ++jj) {
            const int j = (jj << 2) + t;     // interleaved -> bank-disjoint lanes
            float acc = sb1[j];
            const float4* w1r = (const float4*)&sW1T[j * 44];
            #pragma unroll
            for (int q = 0; q < 8; ++q) {    // X part of feats
                float4 w = w1r[q];
                acc = fmaf(X[4*q+0], w.x, acc);
                acc = fmaf(X[4*q+1], w.y, acc);
                acc = fmaf(X[4*q+2], w.z, acc);
                acc = fmaf(X[4*q+3], w.w, acc);
            }
            {
                float4 w = w1r[8];           // Y[0..3]
                acc = fmaf(Y[0], w.x, acc);
                acc = fmaf(Y[1], w.y, acc);
                acc = fmaf(Y[2], w.z, acc);
                acc = fmaf(Y[3], w.w, acc);
            }
            {
                float4 w = w1r[9];           // Y[4..7]
                acc = fmaf(Y[4], w.x, acc);
                acc = fmaf(Y[5], w.y, acc);
                acc = fmaf(Y[6], w.z, acc);
                acc = fmaf(Y[7], w.w, acc);
            }
            {
                float4 w = w1r[10];          // s, t_feat, pad, pad
                acc = fmaf(s,     w.x, acc);
                acc = fmaf(tfeat, w.y, acc);
            }
            const float h = fast_tanh(acc);
            const float4* w2r = (const float4*)&sW2[j * 36];
            #pragma unroll
            for (int q = 0; q < 8; ++q) {
                float4 w = w2r[q];
                Z[4*q+0] = fmaf(h, w.x, Z[4*q+0]);
                Z[4*q+1] = fmaf(h, w.y, Z[4*q+1]);
                Z[4*q+2] = fmaf(h, w.z, Z[4*q+2]);
                Z[4*q+3] = fmaf(h, w.w, Z[4*q+3]);
            }
        }

        // All-reduce partial Z across the 4 lanes of the group, then add b2.
        #pragma unroll
        for (int d = 0; d < 32; ++d) {
            float z = Z[d];
            z += __shfl_xor(z, 1);
            z += __shfl_xor(z, 2);
            Z[d] = z + sb2[d];
        }

        float Wn[32];
        #pragma unroll
        for (int q = 0; q < 8; ++q) {
            Wn[4*q+0] = sqrt_dt * cur[q].x;
            Wn[4*q+1] = sqrt_dt * cur[q].y;
            Wn[4*q+2] = sqrt_dt * cur[q].z;
            Wn[4*q+3] = sqrt_dt * cur[q].w;
        }

        // drift_V = 0.5*sum(Z^2) + sum(control*Z), control = -cr*Z
        //         = (0.5 - cr) * sum(Z^2)
        float sumZ2 = 0.0f, sumZW = 0.0f;
        #pragma unroll
        for (int d = 0; d < 32; ++d) {
            sumZ2 = fmaf(Z[d], Z[d], sumZ2);
            sumZW = fmaf(Z[d], Wn[d], sumZW);
        }
        V += dt * (0.5f - cr) * sumZ2 + sumZW;

        // X += dt*(-theta*X - cr*Z) + Wn   (SIGMA = 1)
        #pragma unroll
        for (int d = 0; d < 32; ++d) {
            X[d] += dt * fmaf(-theta, X[d], -cr * Z[d]) + Wn[d];
        }

        #pragma unroll
        for (int q = 0; q < 8; ++q) cur[q] = nxt[q];
    }

    // Store: thread t writes X components [t*8, t*8+8); t==0 writes V.
    #pragma unroll
    for (int q = 0; q < 4; ++q) {
        if (t == q) {
            float4* xo = (float4*)(outX + (size_t)part * 32 + q * 8);
            xo[0] = make_float4(X[q*8+0], X[q*8+1], X[q*8+2], X[q*8+3]);
            xo[1] = make_float4(X[q*8+4], X[q*8+5], X[q*8+6], X[q*8+7]);
        }
    }
    if (t == 0) outV[part] = V;
}

extern "C" void kernel_launch(void* const* d_in, const int* in_sizes, int n_in,
                              void* d_out, int out_size, void* d_ws, size_t ws_size,
                              hipStream_t stream) {
    const float* obs   = (const float*)d_in[0];
    const float* x0    = (const float*)d_in[1];
    const float* v0    = (const float*)d_in[2];
    const float* noise = (const float*)d_in[3];
    const float* W1    = (const float*)d_in[4];
    const float* b1    = (const float*)d_in[5];
    const float* W2    = (const float*)d_in[6];
    const float* b2    = (const float*)d_in[7];
    const float* th    = (const float*)d_in[8];
    const int*   oi    = (const int*)d_in[9];
    const int*   cr    = (const int*)d_in[10];

    float* outX = (float*)d_out;
    float* outV = outX + (size_t)N_PART * 32;

    dim3 grid(N_PART * 4 / BLOCK);   // 512 blocks x 256 threads = 4 threads/particle
    fused_sde<<<grid, BLOCK, 0, stream>>>(obs, x0, v0, noise, W1, b1, W2, b2,
                                          th, oi, cr, outX, outV);
}

// Round 2
// 396.277 us; speedup vs baseline: 2.8826x; 2.8826x over previous
//
#include <hip/hip_runtime.h>
#include <math.h>

#define NPART 32768
#define MS 50
#define BLOCK 256

typedef __attribute__((ext_vector_type(8))) short bfrag;   // 8 bf16 (4 VGPRs)
typedef __attribute__((ext_vector_type(4))) float ffrag;   // 4 fp32 (MFMA C/D)

// float -> bf16 bits, round-to-nearest-even
__device__ __forceinline__ unsigned short f2bf(float x) {
    unsigned u = __float_as_uint(x);
    u += 0x7fffu + ((u >> 16) & 1u);
    return (unsigned short)(u >> 16);
}

// tanh(x) = 1 - 2/(exp(2x)+1); saturates correctly at +/-inf.
__device__ __forceinline__ float fast_tanh(float x) {
    float e = __expf(2.0f * x);
    return 1.0f - __fdividef(2.0f, e + 1.0f);
}

// One wave = 16 particles. Lane l: p = l&15 (particle), q = l>>4 (quad).
// Lane owns X dims [8q, 8q+8) of particle p == B-operand layout of
// mfma_f32_16x16x32_bf16 (B[k=8q+j][n=p]).
//
// GEMM1: H^T(128x16) = W1^T(128x42pad64) @ F^T(64x16), 8 M-tiles x 2 K-tiles.
// GEMM2: Z^T(32x16)  = W2^T(32x128)      @ H^T(128x16), 2 M-tiles x 4 K-tiles.
// Weights live in registers as A-fragments (A[m=16mt+p][k=32kt+8q+j]).
// C/D layout (row=4q+r, col=p) -> A/B layout (k=8q+j) mismatch fixed by
// wave-private LDS round trips for H (bf16) and Z (fp32).
__global__ __launch_bounds__(BLOCK, 2)
void fused_sde_mfma(const float* __restrict__ obs,
                    const float* __restrict__ x0,
                    const float* __restrict__ v0,
                    const float* __restrict__ noise,
                    const float* __restrict__ gW1,
                    const float* __restrict__ gb1,
                    const float* __restrict__ gW2,
                    const float* __restrict__ gb2,
                    const float* __restrict__ gtheta,
                    const int* __restrict__ gobs_idx,
                    const int* __restrict__ gctrl,
                    float* __restrict__ outX,
                    float* __restrict__ outV)
{
    // pitches padded to kill bank conflicts and keep 16B alignment:
    // H row = 136 bf16 = 272 B (16*17); Z row = 36 fp32 = 144 B (16*9).
    __shared__ __align__(16) unsigned short Hlds[4][16][136];
    __shared__ __align__(16) float Zlds[4][16][36];
    __shared__ __align__(16) float sb1[128];
    __shared__ __align__(16) float sb2[32];

    const int tid  = threadIdx.x;
    const int w    = tid >> 6;   // wave in block
    const int lane = tid & 63;
    const int p    = lane & 15;  // particle column
    const int q    = lane >> 4;  // quad

    if (tid < 128) sb1[tid] = gb1[tid];
    if (tid < 32)  sb2[tid] = gb2[tid];

    const int part = blockIdx.x * 64 + w * 16 + p;

    // ---- stage weights into register A-fragments (one-time) ----
    bfrag A1[8][2];
    #pragma unroll
    for (int mt = 0; mt < 8; ++mt) {
        const int h = 16 * mt + p;
        #pragma unroll
        for (int kt = 0; kt < 2; ++kt) {
            bfrag a;
            #pragma unroll
            for (int j = 0; j < 8; ++j) {
                const int f = 32 * kt + 8 * q + j;          // feature index
                const float wv = (f < 42) ? gW1[f * 128 + h] : 0.0f;
                a[j] = (short)f2bf(wv);
            }
            A1[mt][kt] = a;
        }
    }
    bfrag A2[2][4];
    #pragma unroll
    for (int mt = 0; mt < 2; ++mt) {
        const int d = 16 * mt + p;
        #pragma unroll
        for (int kt = 0; kt < 4; ++kt) {
            bfrag a;
            #pragma unroll
            for (int j = 0; j < 8; ++j) {
                const int h = 32 * kt + 8 * q + j;          // hidden index
                a[j] = (short)f2bf(gW2[h * 32 + d]);
            }
            A2[mt][kt] = a;
        }
    }

    const float theta = gtheta[0];
    const float tfeat = (float)gobs_idx[0];
    const float cr    = (float)gctrl[0];
    const float dt      = 1.0f / (float)MS;
    const float sqrt_dt = sqrtf(dt);

    // B-fragment for K-tile 1 (features 32..63): q0 = Y[0..7], q1 = [s, t, 0..],
    // q2/q3 = 0. Only s varies per step.
    bfrag BY = {0, 0, 0, 0, 0, 0, 0, 0};
    if (q == 0) {
        #pragma unroll
        for (int j = 0; j < 8; ++j) BY[j] = (short)f2bf(obs[j]);
    } else if (q == 1) {
        BY[1] = (short)f2bf(tfeat);
    }

    // ---- per-lane state: X dims [8q, 8q+8) of particle p ----
    float X[8];
    {
        const float4* xp = (const float4*)(x0 + (size_t)part * 32 + 8 * q);
        float4 a = xp[0], b = xp[1];
        X[0] = a.x; X[1] = a.y; X[2] = a.z; X[3] = a.w;
        X[4] = b.x; X[5] = b.y; X[6] = b.z; X[7] = b.w;
    }
    float V = v0[part];   // replicated across the 4 quads

    const float* nbase = noise + (size_t)part * 32 + 8 * q;
    float4 nc0 = ((const float4*)nbase)[0];
    float4 nc1 = ((const float4*)nbase)[1];

    __syncthreads();

    #pragma unroll 1
    for (int m = 0; m < MS; ++m) {
        // prefetch next step's noise (clamped re-read on last iter)
        const int mn = (m + 1 < MS) ? m + 1 : m;
        const float* np = nbase + (size_t)mn * ((size_t)NPART * 32);
        float4 nn0 = ((const float4*)np)[0];
        float4 nn1 = ((const float4*)np)[1];

        // B-fragment K-tile 0: X -> bf16
        bfrag BX;
        #pragma unroll
        for (int j = 0; j < 8; ++j) BX[j] = (short)f2bf(X[j]);

        bfrag B1 = BY;
        if (q == 1) B1[0] = (short)f2bf((float)m * dt);   // s = times[m]

        // ---- GEMM1 + bias + tanh + pack to LDS ----
        unsigned short* hrow = &Hlds[w][p][0];
        #pragma unroll
        for (int mt = 0; mt < 8; ++mt) {
            ffrag c = *(const ffrag*)&sb1[16 * mt + 4 * q];   // bias as C init
            c = __builtin_amdgcn_mfma_f32_16x16x32_bf16(A1[mt][0], BX, c, 0, 0, 0);
            c = __builtin_amdgcn_mfma_f32_16x16x32_bf16(A1[mt][1], B1, c, 0, 0, 0);
            const unsigned int u0 = (unsigned)f2bf(fast_tanh(c[0]))
                                  | ((unsigned)f2bf(fast_tanh(c[1])) << 16);
            const unsigned int u1 = (unsigned)f2bf(fast_tanh(c[2]))
                                  | ((unsigned)f2bf(fast_tanh(c[3])) << 16);
            *(uint2*)&hrow[16 * mt + 4 * q] = make_uint2(u0, u1);  // ds_write_b64
        }

        __syncthreads();   // H: cross-lane RAW (C-layout writes -> B-layout reads)

        // ---- GEMM2 ----
        ffrag C2_0 = *(const ffrag*)&sb2[4 * q];
        ffrag C2_1 = *(const ffrag*)&sb2[16 + 4 * q];
        #pragma unroll
        for (int kt = 0; kt < 4; ++kt) {
            bfrag B2 = *(const bfrag*)&Hlds[w][p][32 * kt + 8 * q];  // ds_read_b128
            C2_0 = __builtin_amdgcn_mfma_f32_16x16x32_bf16(A2[0][kt], B2, C2_0, 0, 0, 0);
            C2_1 = __builtin_amdgcn_mfma_f32_16x16x32_bf16(A2[1][kt], B2, C2_1, 0, 0, 0);
        }

        // Z (C-layout) -> LDS fp32
        *(ffrag*)&Zlds[w][p][4 * q]      = C2_0;
        *(ffrag*)&Zlds[w][p][16 + 4 * q] = C2_1;

        __syncthreads();   // Z: cross-lane RAW

        // read back Z dims [8q, 8q+8) of particle p
        float4 z0 = *(const float4*)&Zlds[w][p][8 * q];
        float4 z1 = *(const float4*)&Zlds[w][p][8 * q + 4];
        float Z[8] = {z0.x, z0.y, z0.z, z0.w, z1.x, z1.y, z1.z, z1.w};

        float Wn[8];
        Wn[0] = sqrt_dt * nc0.x; Wn[1] = sqrt_dt * nc0.y;
        Wn[2] = sqrt_dt * nc0.z; Wn[3] = sqrt_dt * nc0.w;
        Wn[4] = sqrt_dt * nc1.x; Wn[5] = sqrt_dt * nc1.y;
        Wn[6] = sqrt_dt * nc1.z; Wn[7] = sqrt_dt * nc1.w;

        // drift_V = (0.5 - cr) * sum(Z^2);  dV also gets sum(Z*W)
        float s2 = 0.0f, sw = 0.0f;
        #pragma unroll
        for (int j = 0; j < 8; ++j) {
            s2 = fmaf(Z[j], Z[j], s2);
            sw = fmaf(Z[j], Wn[j], sw);
        }
        s2 += __shfl_xor(s2, 16); s2 += __shfl_xor(s2, 32);
        sw += __shfl_xor(sw, 16); sw += __shfl_xor(sw, 32);
        V += dt * (0.5f - cr) * s2 + sw;

        // X += dt*(-theta*X - cr*Z) + Wn
        #pragma unroll
        for (int j = 0; j < 8; ++j)
            X[j] += dt * fmaf(-theta, X[j], -cr * Z[j]) + Wn[j];

        nc0 = nn0; nc1 = nn1;
    }

    // ---- store: lane writes its 8 X dims; quad-0 lanes write V ----
    float4* xout = (float4*)(outX + (size_t)part * 32 + 8 * q);
    xout[0] = make_float4(X[0], X[1], X[2], X[3]);
    xout[1] = make_float4(X[4], X[5], X[6], X[7]);
    if (q == 0) outV[part] = V;
}

extern "C" void kernel_launch(void* const* d_in, const int* in_sizes, int n_in,
                              void* d_out, int out_size, void* d_ws, size_t ws_size,
                              hipStream_t stream) {
    const float* obs   = (const float*)d_in[0];
    const float* x0    = (const float*)d_in[1];
    const float* v0    = (const float*)d_in[2];
    const float* noise = (const float*)d_in[3];
    const float* W1    = (const float*)d_in[4];
    const float* b1    = (const float*)d_in[5];
    const float* W2    = (const float*)d_in[6];
    const float* b2    = (const float*)d_in[7];
    const float* th    = (const float*)d_in[8];
    const int*   oi    = (const int*)d_in[9];
    const int*   cr    = (const int*)d_in[10];

    float* outX = (float*)d_out;
    float* outV = outX + (size_t)NPART * 32;

    dim3 grid(NPART / 64);   // 512 blocks x 4 waves x 16 particles
    fused_sde_mfma<<<grid, BLOCK, 0, stream>>>(obs, x0, v0, noise, W1, b1, W2, b2,
                                               th, oi, cr, outX, outV);
}